// Round 1
// 1699.228 us; speedup vs baseline: 1.0646x; 1.0646x over previous
//
#include <hip/hip_runtime.h>

// ---------------------------------------------------------------------------
// Decagon GCN forward, round 4.
// R3 -> R4: gather was issue-bound on shuffle-broadcast overhead (2 ds_bpermute
// + vector 64b addr calc per edge). Now: CSR rows padded to %8 with zero
// entries, (col,val) fetched via wave-uniform scalar loads (readfirstlane'd
// offsets -> s_load_dwordx8), hw loads use SGPR base + constant lane offset.
// Dispatch fusion: gemm y=4 (all 4 edge types), gather y=2 (both halves),
// hist/reorder y=4, assemble folded into final gather. 33 -> 16 dispatches.
// ---------------------------------------------------------------------------

#define HDIM 64

// C_t[N,64] = act(A_t)[N,K] @ W_t[K,64], t = blockIdx.y in 0..3.
// A_t = (t&1) ? in1 : in0;  W_t = Wall + t*K*64;  C_t = hw + t*N*64.
template <int RELU>
__global__ __launch_bounds__(256) void gemm64(const float* __restrict__ in0,
                                              const float* __restrict__ in1,
                                              const float* __restrict__ Wall,
                                              float* __restrict__ hwout,
                                              int N, int K) {
    __shared__ __align__(16) float Ws[128 * 64];
    __shared__ __align__(16) float As[16 * 68];

    const int t = blockIdx.y;
    const float* A = (t & 1) ? in1 : in0;
    const float* W = Wall + (size_t)t * K * HDIM;
    float*       C = hwout + (size_t)t * (size_t)N * HDIM;

    const int tid  = threadIdx.x;
    const int row0 = blockIdx.x * 64;

    for (int off = tid * 4; off < K * 64; off += 1024) {
        *(float4*)(Ws + off) = *(const float4*)(W + off);
    }

    const int tx = tid & 15;
    const int ty = tid >> 4;
    const int lr = tid >> 2;
    const int kq = tid & 3;

    float acc[4][4];
#pragma unroll
    for (int i = 0; i < 4; i++)
#pragma unroll
        for (int j = 0; j < 4; j++) acc[i][j] = 0.f;

    const int grow = row0 + lr;
    const float* Arow = A + (size_t)grow * K;

    for (int k0 = 0; k0 < K; k0 += 16) {
        __syncthreads();
        float4 av = make_float4(0.f, 0.f, 0.f, 0.f);
        if (grow < N) av = *(const float4*)(Arow + k0 + kq * 4);
        if (RELU) {
            av.x = fmaxf(av.x, 0.f); av.y = fmaxf(av.y, 0.f);
            av.z = fmaxf(av.z, 0.f); av.w = fmaxf(av.w, 0.f);
        }
        As[(kq * 4 + 0) * 68 + lr] = av.x;
        As[(kq * 4 + 1) * 68 + lr] = av.y;
        As[(kq * 4 + 2) * 68 + lr] = av.z;
        As[(kq * 4 + 3) * 68 + lr] = av.w;
        __syncthreads();

#pragma unroll
        for (int kk = 0; kk < 16; kk++) {
            float4 a4 = *(const float4*)(As + kk * 68 + ty * 4);
            float4 b4 = *(const float4*)(Ws + (k0 + kk) * 64 + tx * 4);
            float avv[4] = {a4.x, a4.y, a4.z, a4.w};
            float bvv[4] = {b4.x, b4.y, b4.z, b4.w};
#pragma unroll
            for (int i = 0; i < 4; i++)
#pragma unroll
                for (int j = 0; j < 4; j++)
                    acc[i][j] = fmaf(avv[i], bvv[j], acc[i][j]);
        }
    }

#pragma unroll
    for (int i = 0; i < 4; i++) {
        int r = row0 + ty * 4 + i;
        if (r < N) {
            float4 o = make_float4(acc[i][0], acc[i][1], acc[i][2], acc[i][3]);
            *(float4*)(C + (size_t)r * HDIM + tx * 4) = o;
        }
    }
}

// --- CSR build (padded-to-8 segments) -------------------------------------

__global__ __launch_bounds__(256) void hist4(const int* __restrict__ rows,
                                             int* __restrict__ cnt, int E, int N) {
    int e = blockIdx.x * 256 + threadIdx.x;
    int t = blockIdx.y;
    if (e < E) atomicAdd(&cnt[t * N + rows[(size_t)t * E + e]], 1);
}

__global__ __launch_bounds__(256) void scan_sums(const int* __restrict__ cnt,
                                                 int* __restrict__ partials, int M) {
    __shared__ int red[256];
    int base = blockIdx.x * 1024 + threadIdx.x * 4;
    int s = 0;
#pragma unroll
    for (int j = 0; j < 4; j++) {
        int i = base + j;
        if (i < M) s += (cnt[i] + 7) & ~7;   // padded count
    }
    red[threadIdx.x] = s;
    __syncthreads();
    for (int off = 128; off > 0; off >>= 1) {
        if (threadIdx.x < off) red[threadIdx.x] += red[threadIdx.x + off];
        __syncthreads();
    }
    if (threadIdx.x == 0) partials[blockIdx.x] = red[0];
}

__global__ __launch_bounds__(1024) void scan_partials(int* __restrict__ partials, int B) {
    __shared__ int buf[1024];
    int t = threadIdx.x;
    int v = (t < B) ? partials[t] : 0;
    buf[t] = v;
    __syncthreads();
    for (int off = 1; off < 1024; off <<= 1) {
        int add = (t >= off) ? buf[t - off] : 0;
        __syncthreads();
        buf[t] += add;
        __syncthreads();
    }
    if (t < B) partials[t] = buf[t] - v;  // exclusive
}

__global__ __launch_bounds__(256) void scan_final(int* __restrict__ cnt,
                                                  const int* __restrict__ partials,
                                                  int* __restrict__ start, int M) {
    __shared__ int red[256];
    int tid = threadIdx.x;
    int base = blockIdx.x * 1024 + tid * 4;
    int v[4];
    int s = 0;
#pragma unroll
    for (int j = 0; j < 4; j++) {
        int i = base + j;
        v[j] = (i < M) ? ((cnt[i] + 7) & ~7) : 0;   // padded count
        s += v[j];
    }
    red[tid] = s;
    __syncthreads();
    int mine = s;
    for (int off = 1; off < 256; off <<= 1) {
        int add = (tid >= off) ? red[tid - off] : 0;
        __syncthreads();
        red[tid] += add;
        __syncthreads();
    }
    int excl = red[tid] - mine + partials[blockIdx.x];
#pragma unroll
    for (int j = 0; j < 4; j++) {
        int i = base + j;
        if (i < M) {
            start[i] = excl;
            cnt[i]   = excl;    // reorder cursor starts at segment base
            excl += v[j];
            if (i == M - 1) start[M] = excl;   // padded total
        }
    }
}

__global__ __launch_bounds__(256) void reorder4(const int* __restrict__ rows,
                                                const int* __restrict__ cols,
                                                const float* __restrict__ vals,
                                                int* __restrict__ cursor,
                                                int* __restrict__ scol,
                                                float* __restrict__ sval, int E, int N) {
    int e = blockIdx.x * 256 + threadIdx.x;
    int t = blockIdx.y;
    if (e >= E) return;
    size_t o = (size_t)t * E + e;
    int pos = atomicAdd(&cursor[t * N + rows[o]], 1);
    scol[pos] = cols[o];
    sval[pos] = vals[o];
}

// --- fused gather: one wave per (half,row), scalarized CSR ------------------
// half = blockIdx.y; out_half[row] = sum over types t=2*half, 2*half+1 of
//   sum_{e in seg(t,row)} sval[e] * hw_t[scol[e]][lane].
// Segments padded to %8 with (col=0,val=0) so the 8-wide inner block needs no
// guards. beg/end forced into SGPRs -> (col,val) reads become s_load_dwordx8,
// hw addressing is SGPR-base + constant lane offset (no per-lane addr math).
template <int FINAL>
__global__ __launch_bounds__(256) void gather4(const float* __restrict__ hw,
                                               const int* __restrict__ start,
                                               const int* __restrict__ scol,
                                               const float* __restrict__ sval,
                                               float* __restrict__ o0,
                                               float* __restrict__ o1,
                                               const float* __restrict__ h1,
                                               const float* __restrict__ e1,
                                               const float* __restrict__ att,
                                               float* __restrict__ outF,
                                               int N) {
    const int half = blockIdx.y;
    const int row  = blockIdx.x * 4 + (threadIdx.x >> 6);
    const int lane = threadIdx.x & 63;
    if (row >= N) return;

    const size_t NH = (size_t)N * HDIM;
    float accA = 0.f, accB = 0.f;

#pragma unroll
    for (int p = 0; p < 2; p++) {
        const int t = half * 2 + p;
        const float* __restrict__ h = hw + (size_t)t * NH;
        int beg = __builtin_amdgcn_readfirstlane(start[t * N + row]);
        int end = __builtin_amdgcn_readfirstlane(start[t * N + row + 1]);
        for (int e = beg; e < end; e += 8) {
            int   c[8];
            float v[8];
#pragma unroll
            for (int u = 0; u < 8; u++) {   // uniform addresses -> s_load_dwordx8
                c[u] = scol[e + u];
                v[u] = sval[e + u];
            }
            float hv[8];
#pragma unroll
            for (int u = 0; u < 8; u++)
                hv[u] = h[(size_t)c[u] * HDIM + lane];
#pragma unroll
            for (int u = 0; u < 8; u += 2) {
                accA = fmaf(v[u],     hv[u],     accA);
                accB = fmaf(v[u + 1], hv[u + 1], accB);
            }
        }
    }

    float r = accA + accB;
    if (!FINAL) {
        float* o = half ? o1 : o0;
        o[(size_t)row * HDIM + lane] = r;
    } else {
        // epilogue fused: emb = p + relu(h1); concat(relu(h1)*a0, relu(e1)*a1, emb*a2)
        size_t idx = (size_t)half * NH + (size_t)row * HDIM + lane;
        float hh = fmaxf(h1[idx], 0.f);
        float ee = fmaxf(e1[idx], 0.f);
        size_t base = (size_t)half * N * 192 + (size_t)row * 192 + lane;
        outF[base]       = hh * att[0];
        outF[base + 64]  = ee * att[1];
        outF[base + 128] = (r + hh) * att[2];
    }
}

extern "C" void kernel_launch(void* const* d_in, const int* in_sizes, int n_in,
                              void* d_out, int out_size, void* d_ws, size_t ws_size,
                              hipStream_t stream) {
    const float* feat0 = (const float*)d_in[0];
    const float* feat1 = (const float*)d_in[1];
    const int*   rows  = (const int*)d_in[2];
    const int*   cols  = (const int*)d_in[3];
    const float* vals  = (const float*)d_in[4];
    const float* W1    = (const float*)d_in[5];
    const float* W2    = (const float*)d_in[6];
    const float* W3    = (const float*)d_in[7];
    const float* W4    = (const float*)d_in[8];
    const float* W5    = (const float*)d_in[9];
    const float* att   = (const float*)d_in[10];

    const int N = in_sizes[0] / 128;   // 100000
    const int E = in_sizes[2] / 4;     // 1000000
    const size_t NH = (size_t)N * HDIM;
    const int M = 4 * N;
    const int PadCap = 4 * E + 7 * M;  // max padded CSR entries

    float* ws  = (float*)d_ws;
    // persistent activations (8*NH) + hw staging (4*NH)
    float* h10 = ws + 0 * NH;          // h1 halves (contiguous 2*NH)
    float* e10 = ws + 2 * NH;          // e1 halves (contiguous 2*NH)
    float* A0  = ws + 4 * NH;          // ping (e2, reused)
    float* A1  = ws + 5 * NH;
    float* B0  = ws + 6 * NH;          // pong (e3)
    float* B1  = ws + 7 * NH;
    float* hw  = ws + 8 * NH;          // 4*NH: hw_t = act(h_{t&1}) @ W_t

    // CSR arrays first for 32B alignment of scol (s_load_dwordx8 merges)
    int*   scol     = (int*)(ws + 12 * NH);       // PadCap
    float* sval     = (float*)(scol + PadCap);    // PadCap (27.2MB offset, 32B-aligned)
    int*   start    = (int*)(sval + PadCap);      // M+1
    int*   cursor   = start + (M + 1);            // M
    int*   partials = cursor + M;                 // <=1024

    const int gblk = (N + 63) / 64;
    const int eblk = (E + 255) / 256;
    const int B    = (M + 1023) / 1024;
    const int gr2  = (N + 3) / 4;

    // ---- CSR build (once; graph reused by all 5 layers) ----
    hipMemsetAsync(cursor, 0, (size_t)M * sizeof(int), stream);
    hipMemsetAsync(scol, 0, (size_t)PadCap * 2 * sizeof(int), stream);  // pad entries -> col=0,val=0
    hist4<<<dim3(eblk, 4), 256, 0, stream>>>(rows, cursor, E, N);
    scan_sums<<<B, 256, 0, stream>>>(cursor, partials, M);
    scan_partials<<<1, 1024, 0, stream>>>(partials, B);
    scan_final<<<B, 256, 0, stream>>>(cursor, partials, start, M);
    reorder4<<<dim3(eblk, 4), 256, 0, stream>>>(rows, cols, vals, cursor, scol, sval, E, N);

    auto layer = [&](const float* in0, const float* in1, const float* W, int K,
                     bool relu_in, float* o0, float* o1, bool fin) {
        dim3 ggrid(gblk, 4);
        if (relu_in)
            gemm64<1><<<ggrid, 256, 0, stream>>>(in0, in1, W, hw, N, K);
        else
            gemm64<0><<<ggrid, 256, 0, stream>>>(in0, in1, W, hw, N, K);
        dim3 sgrid(gr2, 2);
        if (!fin)
            gather4<0><<<sgrid, 256, 0, stream>>>(hw, start, scol, sval, o0, o1,
                                                  nullptr, nullptr, nullptr, nullptr, N);
        else
            gather4<1><<<sgrid, 256, 0, stream>>>(hw, start, scol, sval, nullptr, nullptr,
                                                  h10, e10, att, (float*)d_out, N);
    };

    layer(feat0, feat1, W1, 128, false, h10, h10 + NH, false);  // -> h1 (pre-act)
    layer(h10, h10 + NH, W2, 64, true, e10, e10 + NH, false);   // -> e1 (pre-act)
    layer(e10, e10 + NH, W3, 64, true, A0, A1, false);          // -> e2
    layer(A0, A1, W4, 64, true, B0, B1, false);                 // -> e3
    layer(B0, B1, W5, 64, true, nullptr, nullptr, true);        // -> p, fused epilogue
}

// Round 3
// 1653.452 us; speedup vs baseline: 1.0940x; 1.0277x over previous
//
#include <hip/hip_runtime.h>

// ---------------------------------------------------------------------------
// Decagon GCN forward, round 5 (resubmit — R5 bench was an infra failure:
// "container failed twice", no pytest/rocprof output; source re-audited, no
// defect found, resubmitting unchanged to preserve the A/B vs R4).
// R4 -> R5:
//  * reorder was the top kernel (270us, 387MB WRITE for 32MB payload): two
//    random 4B stores per edge -> one int2 (col,val) 8B store. Gather now
//    reads pairs as s_load_dwordx16 (4 x int4 per 8 edges).
//  * layers 2-5 switched to gather-first: g_t = adj_t @ relu(in_j) gathers the
//    51MB input tables instead of the 102MB post-GEMM hw tables (better L2/L3
//    hit rate on the dominant random-read stream), then one K=128 GEMM per
//    half: out_h = [g_2h | g_2h+1] @ [W_2h ; W_2h+1] (contiguous W pairs).
//    Final-layer GEMM fuses the attention/concat epilogue.
// ---------------------------------------------------------------------------

#define HDIM 64

// ---- layer-1 GEMM: C_t[N,64] = feat_{t&1}[N,128] @ W1_t[128,64], t=blockIdx.y
__global__ __launch_bounds__(256) void gemm_l1(const float* __restrict__ in0,
                                               const float* __restrict__ in1,
                                               const float* __restrict__ Wall,
                                               float* __restrict__ hwout, int N) {
    const int K = 128;
    __shared__ __align__(16) float Ws[128 * 64];
    __shared__ __align__(16) float As[16 * 68];

    const int t = blockIdx.y;
    const float* A = (t & 1) ? in1 : in0;
    const float* W = Wall + (size_t)t * K * HDIM;
    float*       C = hwout + (size_t)t * (size_t)N * HDIM;

    const int tid  = threadIdx.x;
    const int row0 = blockIdx.x * 64;

    for (int off = tid * 4; off < K * 64; off += 1024)
        *(float4*)(Ws + off) = *(const float4*)(W + off);

    const int tx = tid & 15;
    const int ty = tid >> 4;
    const int lr = tid >> 2;
    const int kq = tid & 3;

    float acc[4][4];
#pragma unroll
    for (int i = 0; i < 4; i++)
#pragma unroll
        for (int j = 0; j < 4; j++) acc[i][j] = 0.f;

    const int grow = row0 + lr;
    const float* Arow = A + (size_t)grow * K;

    for (int k0 = 0; k0 < K; k0 += 16) {
        __syncthreads();
        float4 av = make_float4(0.f, 0.f, 0.f, 0.f);
        if (grow < N) av = *(const float4*)(Arow + k0 + kq * 4);
        As[(kq * 4 + 0) * 68 + lr] = av.x;
        As[(kq * 4 + 1) * 68 + lr] = av.y;
        As[(kq * 4 + 2) * 68 + lr] = av.z;
        As[(kq * 4 + 3) * 68 + lr] = av.w;
        __syncthreads();

#pragma unroll
        for (int kk = 0; kk < 16; kk++) {
            float4 a4 = *(const float4*)(As + kk * 68 + ty * 4);
            float4 b4 = *(const float4*)(Ws + (k0 + kk) * 64 + tx * 4);
            float avv[4] = {a4.x, a4.y, a4.z, a4.w};
            float bvv[4] = {b4.x, b4.y, b4.z, b4.w};
#pragma unroll
            for (int i = 0; i < 4; i++)
#pragma unroll
                for (int j = 0; j < 4; j++)
                    acc[i][j] = fmaf(avv[i], bvv[j], acc[i][j]);
        }
    }

#pragma unroll
    for (int i = 0; i < 4; i++) {
        int r = row0 + ty * 4 + i;
        if (r < N) {
            float4 o = make_float4(acc[i][0], acc[i][1], acc[i][2], acc[i][3]);
            *(float4*)(C + (size_t)r * HDIM + tx * 4) = o;
        }
    }
}

// ---- layers 2-5 GEMM: C_h[N,64] = g_h[N,128] @ Wstack_h[128,64], h=blockIdx.y
// FIN: fuse epilogue  out = concat(relu(h1)*a0, relu(e1)*a1, (p+relu(h1))*a2)
template <int FIN>
__global__ __launch_bounds__(256) void gemm_h2(const float* __restrict__ g,
                                               const float* __restrict__ Wl,
                                               float* __restrict__ outp,
                                               const float* __restrict__ h1,
                                               const float* __restrict__ e1,
                                               const float* __restrict__ att,
                                               float* __restrict__ outF, int N) {
    const int K = 128;
    __shared__ __align__(16) float Ws[128 * 64];
    __shared__ __align__(16) float As[16 * 68];

    const int t = blockIdx.y;
    const size_t NH = (size_t)N * HDIM;
    const float* A = g + (size_t)t * (size_t)N * K;
    const float* W = Wl + (size_t)t * 8192;   // [W_{2t}; W_{2t+1}] contiguous

    const int tid  = threadIdx.x;
    const int row0 = blockIdx.x * 64;

    for (int off = tid * 4; off < K * 64; off += 1024)
        *(float4*)(Ws + off) = *(const float4*)(W + off);

    const int tx = tid & 15;
    const int ty = tid >> 4;
    const int lr = tid >> 2;
    const int kq = tid & 3;

    float acc[4][4];
#pragma unroll
    for (int i = 0; i < 4; i++)
#pragma unroll
        for (int j = 0; j < 4; j++) acc[i][j] = 0.f;

    const int grow = row0 + lr;
    const float* Arow = A + (size_t)grow * K;

    for (int k0 = 0; k0 < K; k0 += 16) {
        __syncthreads();
        float4 av = make_float4(0.f, 0.f, 0.f, 0.f);
        if (grow < N) av = *(const float4*)(Arow + k0 + kq * 4);
        As[(kq * 4 + 0) * 68 + lr] = av.x;
        As[(kq * 4 + 1) * 68 + lr] = av.y;
        As[(kq * 4 + 2) * 68 + lr] = av.z;
        As[(kq * 4 + 3) * 68 + lr] = av.w;
        __syncthreads();

#pragma unroll
        for (int kk = 0; kk < 16; kk++) {
            float4 a4 = *(const float4*)(As + kk * 68 + ty * 4);
            float4 b4 = *(const float4*)(Ws + (k0 + kk) * 64 + tx * 4);
            float avv[4] = {a4.x, a4.y, a4.z, a4.w};
            float bvv[4] = {b4.x, b4.y, b4.z, b4.w};
#pragma unroll
            for (int i = 0; i < 4; i++)
#pragma unroll
                for (int j = 0; j < 4; j++)
                    acc[i][j] = fmaf(avv[i], bvv[j], acc[i][j]);
        }
    }

    if (!FIN) {
        float* C = outp + (size_t)t * NH;
#pragma unroll
        for (int i = 0; i < 4; i++) {
            int r = row0 + ty * 4 + i;
            if (r < N) {
                float4 o = make_float4(acc[i][0], acc[i][1], acc[i][2], acc[i][3]);
                *(float4*)(C + (size_t)r * HDIM + tx * 4) = o;
            }
        }
    } else {
        const float a0 = att[0], a1 = att[1], a2 = att[2];
#pragma unroll
        for (int i = 0; i < 4; i++) {
            int r = row0 + ty * 4 + i;
            if (r < N) {
                size_t idx = (size_t)t * NH + (size_t)r * HDIM + tx * 4;
                float4 h4 = *(const float4*)(h1 + idx);
                float4 e4 = *(const float4*)(e1 + idx);
                float hh[4] = {fmaxf(h4.x, 0.f), fmaxf(h4.y, 0.f),
                               fmaxf(h4.z, 0.f), fmaxf(h4.w, 0.f)};
                float ee[4] = {fmaxf(e4.x, 0.f), fmaxf(e4.y, 0.f),
                               fmaxf(e4.z, 0.f), fmaxf(e4.w, 0.f)};
                size_t base = (size_t)t * (size_t)N * 192 + (size_t)r * 192 + tx * 4;
                *(float4*)(outF + base) =
                    make_float4(hh[0] * a0, hh[1] * a0, hh[2] * a0, hh[3] * a0);
                *(float4*)(outF + base + 64) =
                    make_float4(ee[0] * a1, ee[1] * a1, ee[2] * a1, ee[3] * a1);
                *(float4*)(outF + base + 128) =
                    make_float4((acc[i][0] + hh[0]) * a2, (acc[i][1] + hh[1]) * a2,
                                (acc[i][2] + hh[2]) * a2, (acc[i][3] + hh[3]) * a2);
            }
        }
    }
}

// --- CSR build (padded-to-8 segments, interleaved (col,val) pairs) ---------

__global__ __launch_bounds__(256) void hist4(const int* __restrict__ rows,
                                             int* __restrict__ cnt, int E, int N) {
    int e = blockIdx.x * 256 + threadIdx.x;
    int t = blockIdx.y;
    if (e < E) atomicAdd(&cnt[t * N + rows[(size_t)t * E + e]], 1);
}

__global__ __launch_bounds__(256) void scan_sums(const int* __restrict__ cnt,
                                                 int* __restrict__ partials, int M) {
    __shared__ int red[256];
    int base = blockIdx.x * 1024 + threadIdx.x * 4;
    int s = 0;
#pragma unroll
    for (int j = 0; j < 4; j++) {
        int i = base + j;
        if (i < M) s += (cnt[i] + 7) & ~7;
    }
    red[threadIdx.x] = s;
    __syncthreads();
    for (int off = 128; off > 0; off >>= 1) {
        if (threadIdx.x < off) red[threadIdx.x] += red[threadIdx.x + off];
        __syncthreads();
    }
    if (threadIdx.x == 0) partials[blockIdx.x] = red[0];
}

__global__ __launch_bounds__(1024) void scan_partials(int* __restrict__ partials, int B) {
    __shared__ int buf[1024];
    int t = threadIdx.x;
    int v = (t < B) ? partials[t] : 0;
    buf[t] = v;
    __syncthreads();
    for (int off = 1; off < 1024; off <<= 1) {
        int add = (t >= off) ? buf[t - off] : 0;
        __syncthreads();
        buf[t] += add;
        __syncthreads();
    }
    if (t < B) partials[t] = buf[t] - v;  // exclusive
}

__global__ __launch_bounds__(256) void scan_final(int* __restrict__ cnt,
                                                  const int* __restrict__ partials,
                                                  int* __restrict__ start, int M) {
    __shared__ int red[256];
    int tid = threadIdx.x;
    int base = blockIdx.x * 1024 + tid * 4;
    int v[4];
    int s = 0;
#pragma unroll
    for (int j = 0; j < 4; j++) {
        int i = base + j;
        v[j] = (i < M) ? ((cnt[i] + 7) & ~7) : 0;
        s += v[j];
    }
    red[tid] = s;
    __syncthreads();
    int mine = s;
    for (int off = 1; off < 256; off <<= 1) {
        int add = (tid >= off) ? red[tid - off] : 0;
        __syncthreads();
        red[tid] += add;
        __syncthreads();
    }
    int excl = red[tid] - mine + partials[blockIdx.x];
#pragma unroll
    for (int j = 0; j < 4; j++) {
        int i = base + j;
        if (i < M) {
            start[i] = excl;
            cnt[i]   = excl;          // reorder cursor starts at segment base
            excl += v[j];
            if (i == M - 1) start[M] = excl;
        }
    }
}

__global__ __launch_bounds__(256) void reorder4(const int* __restrict__ rows,
                                                const int* __restrict__ cols,
                                                const float* __restrict__ vals,
                                                int* __restrict__ cursor,
                                                int2* __restrict__ spair,
                                                int E, int N) {
    int e = blockIdx.x * 256 + threadIdx.x;
    int t = blockIdx.y;
    if (e >= E) return;
    size_t o = (size_t)t * E + e;
    int pos = atomicAdd(&cursor[t * N + rows[o]], 1);
    spair[pos] = make_int2(cols[o], __float_as_int(vals[o]));   // one 8B store
}

// --- gathers ---------------------------------------------------------------
// Pairs: segments padded to %8 with (col=0,val=0). Per 8 edges: 4 uniform
// int4 loads (s_load_dwordx16) + 8 per-lane row loads + 8 fma.

// layer 1 (gather-after): out_h[row] = sum_{t=2h,2h+1} adj_t-row . hw_t
__global__ __launch_bounds__(256) void gatherA(const float* __restrict__ hw,
                                               const int* __restrict__ start,
                                               const int4* __restrict__ sp4,
                                               float* __restrict__ h1out, int N) {
    const int half = blockIdx.y;
    const int row  = blockIdx.x * 4 + (threadIdx.x >> 6);
    const int lane = threadIdx.x & 63;
    if (row >= N) return;
    const size_t NH = (size_t)N * HDIM;
    float accA = 0.f, accB = 0.f;

#pragma unroll
    for (int p = 0; p < 2; p++) {
        const int tt = half * 2 + p;
        const float* __restrict__ h = hw + (size_t)tt * NH;
        int beg = __builtin_amdgcn_readfirstlane(start[tt * N + row]);
        int end = __builtin_amdgcn_readfirstlane(start[tt * N + row + 1]);
        for (int e = beg; e < end; e += 8) {
            int c[8]; float v[8];
#pragma unroll
            for (int u = 0; u < 4; u++) {
                int4 q = sp4[(e >> 1) + u];
                c[2 * u]     = q.x; v[2 * u]     = __int_as_float(q.y);
                c[2 * u + 1] = q.z; v[2 * u + 1] = __int_as_float(q.w);
            }
            float hv[8];
#pragma unroll
            for (int u = 0; u < 8; u++)
                hv[u] = h[(size_t)c[u] * HDIM + lane];
#pragma unroll
            for (int u = 0; u < 8; u += 2) {
                accA = fmaf(v[u],     hv[u],     accA);
                accB = fmaf(v[u + 1], hv[u + 1], accB);
            }
        }
    }
    h1out[(size_t)half * NH + (size_t)row * HDIM + lane] = accA + accB;
}

// layers 2-5 (gather-first): g_h[row][p*64+lane] = adj_{2h+p}-row . relu(in_{p})
__global__ __launch_bounds__(256) void gatherF(const float* __restrict__ in,
                                               const int* __restrict__ start,
                                               const int4* __restrict__ sp4,
                                               float* __restrict__ g, int N) {
    const int half = blockIdx.y;
    const int row  = blockIdx.x * 4 + (threadIdx.x >> 6);
    const int lane = threadIdx.x & 63;
    if (row >= N) return;
    const size_t NH = (size_t)N * HDIM;
    float* gout = g + ((size_t)half * N + row) * 128 + lane;

#pragma unroll
    for (int p = 0; p < 2; p++) {
        const int tt = half * 2 + p;
        const float* __restrict__ h = in + (size_t)(tt & 1) * NH;
        int beg = __builtin_amdgcn_readfirstlane(start[tt * N + row]);
        int end = __builtin_amdgcn_readfirstlane(start[tt * N + row + 1]);
        float accA = 0.f, accB = 0.f;
        for (int e = beg; e < end; e += 8) {
            int c[8]; float v[8];
#pragma unroll
            for (int u = 0; u < 4; u++) {
                int4 q = sp4[(e >> 1) + u];
                c[2 * u]     = q.x; v[2 * u]     = __int_as_float(q.y);
                c[2 * u + 1] = q.z; v[2 * u + 1] = __int_as_float(q.w);
            }
            float hv[8];
#pragma unroll
            for (int u = 0; u < 8; u++)
                hv[u] = fmaxf(h[(size_t)c[u] * HDIM + lane], 0.f);  // relu on load
#pragma unroll
            for (int u = 0; u < 8; u += 2) {
                accA = fmaf(v[u],     hv[u],     accA);
                accB = fmaf(v[u + 1], hv[u + 1], accB);
            }
        }
        gout[p * 64] = accA + accB;
    }
}

extern "C" void kernel_launch(void* const* d_in, const int* in_sizes, int n_in,
                              void* d_out, int out_size, void* d_ws, size_t ws_size,
                              hipStream_t stream) {
    const float* feat0 = (const float*)d_in[0];
    const float* feat1 = (const float*)d_in[1];
    const int*   rows  = (const int*)d_in[2];
    const int*   cols  = (const int*)d_in[3];
    const float* vals  = (const float*)d_in[4];
    const float* W1    = (const float*)d_in[5];
    const float* W2    = (const float*)d_in[6];
    const float* W3    = (const float*)d_in[7];
    const float* W4    = (const float*)d_in[8];
    const float* W5    = (const float*)d_in[9];
    const float* att   = (const float*)d_in[10];

    const int N = in_sizes[0] / 128;   // 100000
    const int E = in_sizes[2] / 4;     // 1000000
    const size_t NH = (size_t)N * HDIM;
    const int M = 4 * N;
    const int PadCap = 4 * E + 7 * M;  // max padded CSR entries

    float* ws  = (float*)d_ws;
    float* h10 = ws + 0 * NH;          // h1 halves (2*NH, pre-act)
    float* e10 = ws + 2 * NH;          // e1 halves (2*NH, pre-act)
    float* A0  = ws + 4 * NH;          // e2 (2*NH)
    float* B0  = ws + 6 * NH;          // e3 (2*NH)
    float* hwg = ws + 8 * NH;          // 4*NH: layer1 hw tables OR g [2][N][128]

    int2*  spair    = (int2*)(ws + 12 * NH);       // PadCap pairs (16B-aligned)
    int*   start    = (int*)(spair + PadCap);      // M+1
    int*   cursor   = start + (M + 1);             // M
    int*   partials = cursor + M;                  // <=1024

    const int gblk = (N + 63) / 64;
    const int eblk = (E + 255) / 256;
    const int B    = (M + 1023) / 1024;
    const int gr2  = (N + 3) / 4;

    // ---- CSR build (once; graph reused by all 5 layers) ----
    hipMemsetAsync(cursor, 0, (size_t)M * sizeof(int), stream);
    hipMemsetAsync(spair, 0, (size_t)PadCap * sizeof(int2), stream);  // pads -> (0,0)
    hist4<<<dim3(eblk, 4), 256, 0, stream>>>(rows, cursor, E, N);
    scan_sums<<<B, 256, 0, stream>>>(cursor, partials, M);
    scan_partials<<<1, 1024, 0, stream>>>(partials, B);
    scan_final<<<B, 256, 0, stream>>>(cursor, partials, start, M);
    reorder4<<<dim3(eblk, 4), 256, 0, stream>>>(rows, cols, vals, cursor, spair, E, N);

    const int4* sp4 = (const int4*)spair;

    // ---- layer 1: GEMM-first (feat is 128-wide), gather-after ----
    gemm_l1<<<dim3(gblk, 4), 256, 0, stream>>>(feat0, feat1, W1, hwg, N);
    gatherA<<<dim3(gr2, 2), 256, 0, stream>>>(hwg, start, sp4, h10, N);

    // ---- layers 2-4: gather-first (relu in gather), then K=128 GEMM ----
    const float* ins[3]  = {h10, e10, A0};
    float*       outs[3] = {e10, A0, B0};
    const float* Wls[3]  = {W2, W3, W4};
    for (int l = 0; l < 3; l++) {
        gatherF<<<dim3(gr2, 2), 256, 0, stream>>>(ins[l], start, sp4, hwg, N);
        gemm_h2<0><<<dim3(gblk, 2), 256, 0, stream>>>(hwg, Wls[l], outs[l],
                                                      nullptr, nullptr, nullptr,
                                                      nullptr, N);
    }

    // ---- layer 5: gather-first + GEMM with fused attention/concat epilogue ----
    gatherF<<<dim3(gr2, 2), 256, 0, stream>>>(B0, start, sp4, hwg, N);
    gemm_h2<1><<<dim3(gblk, 2), 256, 0, stream>>>(hwg, W5, nullptr,
                                                  h10, e10, att, (float*)d_out, N);
}

// Round 4
// 1470.843 us; speedup vs baseline: 1.2299x; 1.1242x over previous
//
#include <hip/hip_runtime.h>
#include <hip/hip_fp16.h>

// ---------------------------------------------------------------------------
// Decagon GCN forward, round 6.
// R5 -> R6: gathers are ~65% of runtime (5 x ~210us), bound on random
// line-granular reads of 256B fp32 rows (1.05 GB/pass served mostly by L3 at
// ~4.5 TB/s effective). All gather-feeding tables (hw, h1, e1, e2, e3) now
// stored fp16: row = 128B = 2 lines -> bytes and line-requests halve.
// fp32 kept for: accumulators, g, GEMMs, epilogue copies of h1/e1 (one
// quantization point per layer, e5m10 rel err ~5e-4, contracted by W~0.05).
// reorder (240us, line-granular scatter) deliberately untouched this round.
// ---------------------------------------------------------------------------

#define HDIM 64

__device__ inline unsigned pack2h(float a, float b) {
    return (unsigned)__half_as_ushort(__float2half_rn(a)) |
           ((unsigned)__half_as_ushort(__float2half_rn(b)) << 16);
}

// ---- layer-1 GEMM: hw16_t[N,64] = feat_{t&1}[N,128] @ W1_t[128,64], t=blockIdx.y
__global__ __launch_bounds__(256) void gemm_l1(const float* __restrict__ in0,
                                               const float* __restrict__ in1,
                                               const float* __restrict__ Wall,
                                               __half* __restrict__ hw16, int N) {
    const int K = 128;
    __shared__ __align__(16) float Ws[128 * 64];
    __shared__ __align__(16) float As[16 * 68];

    const int t = blockIdx.y;
    const float* A = (t & 1) ? in1 : in0;
    const float* W = Wall + (size_t)t * K * HDIM;
    __half*      C = hw16 + (size_t)t * (size_t)N * HDIM;

    const int tid  = threadIdx.x;
    const int row0 = blockIdx.x * 64;

    for (int off = tid * 4; off < K * 64; off += 1024)
        *(float4*)(Ws + off) = *(const float4*)(W + off);

    const int tx = tid & 15;
    const int ty = tid >> 4;
    const int lr = tid >> 2;
    const int kq = tid & 3;

    float acc[4][4];
#pragma unroll
    for (int i = 0; i < 4; i++)
#pragma unroll
        for (int j = 0; j < 4; j++) acc[i][j] = 0.f;

    const int grow = row0 + lr;
    const float* Arow = A + (size_t)grow * K;

    for (int k0 = 0; k0 < K; k0 += 16) {
        __syncthreads();
        float4 av = make_float4(0.f, 0.f, 0.f, 0.f);
        if (grow < N) av = *(const float4*)(Arow + k0 + kq * 4);
        As[(kq * 4 + 0) * 68 + lr] = av.x;
        As[(kq * 4 + 1) * 68 + lr] = av.y;
        As[(kq * 4 + 2) * 68 + lr] = av.z;
        As[(kq * 4 + 3) * 68 + lr] = av.w;
        __syncthreads();

#pragma unroll
        for (int kk = 0; kk < 16; kk++) {
            float4 a4 = *(const float4*)(As + kk * 68 + ty * 4);
            float4 b4 = *(const float4*)(Ws + (k0 + kk) * 64 + tx * 4);
            float avv[4] = {a4.x, a4.y, a4.z, a4.w};
            float bvv[4] = {b4.x, b4.y, b4.z, b4.w};
#pragma unroll
            for (int i = 0; i < 4; i++)
#pragma unroll
                for (int j = 0; j < 4; j++)
                    acc[i][j] = fmaf(avv[i], bvv[j], acc[i][j]);
        }
    }

#pragma unroll
    for (int i = 0; i < 4; i++) {
        int r = row0 + ty * 4 + i;
        if (r < N) {
            uint2 pk;
            pk.x = pack2h(acc[i][0], acc[i][1]);
            pk.y = pack2h(acc[i][2], acc[i][3]);
            *(uint2*)(C + (size_t)r * HDIM + tx * 4) = pk;
        }
    }
}

// ---- layers 2-5 GEMM: C_h[N,64] = g_h[N,128] @ Wstack_h[128,64], h=blockIdx.y
// MODE 0: fp16 pre-act only (e2,e3).  MODE 1: fp16 + fp32 pre-act (e1).
// MODE 2: FIN epilogue  out = concat(relu(h1)*a0, relu(e1)*a1, (p+relu(h1))*a2)
template <int MODE>
__global__ __launch_bounds__(256) void gemm_h2(const float* __restrict__ g,
                                               const float* __restrict__ Wl,
                                               __half* __restrict__ o16,
                                               float* __restrict__ o32,
                                               const float* __restrict__ h1,
                                               const float* __restrict__ e1,
                                               const float* __restrict__ att,
                                               float* __restrict__ outF, int N) {
    const int K = 128;
    __shared__ __align__(16) float Ws[128 * 64];
    __shared__ __align__(16) float As[16 * 68];

    const int t = blockIdx.y;
    const size_t NH = (size_t)N * HDIM;
    const float* A = g + (size_t)t * (size_t)N * K;
    const float* W = Wl + (size_t)t * 8192;   // [W_{2t}; W_{2t+1}] contiguous

    const int tid  = threadIdx.x;
    const int row0 = blockIdx.x * 64;

    for (int off = tid * 4; off < K * 64; off += 1024)
        *(float4*)(Ws + off) = *(const float4*)(W + off);

    const int tx = tid & 15;
    const int ty = tid >> 4;
    const int lr = tid >> 2;
    const int kq = tid & 3;

    float acc[4][4];
#pragma unroll
    for (int i = 0; i < 4; i++)
#pragma unroll
        for (int j = 0; j < 4; j++) acc[i][j] = 0.f;

    const int grow = row0 + lr;
    const float* Arow = A + (size_t)grow * K;

    for (int k0 = 0; k0 < K; k0 += 16) {
        __syncthreads();
        float4 av = make_float4(0.f, 0.f, 0.f, 0.f);
        if (grow < N) av = *(const float4*)(Arow + k0 + kq * 4);
        As[(kq * 4 + 0) * 68 + lr] = av.x;
        As[(kq * 4 + 1) * 68 + lr] = av.y;
        As[(kq * 4 + 2) * 68 + lr] = av.z;
        As[(kq * 4 + 3) * 68 + lr] = av.w;
        __syncthreads();

#pragma unroll
        for (int kk = 0; kk < 16; kk++) {
            float4 a4 = *(const float4*)(As + kk * 68 + ty * 4);
            float4 b4 = *(const float4*)(Ws + (k0 + kk) * 64 + tx * 4);
            float avv[4] = {a4.x, a4.y, a4.z, a4.w};
            float bvv[4] = {b4.x, b4.y, b4.z, b4.w};
#pragma unroll
            for (int i = 0; i < 4; i++)
#pragma unroll
                for (int j = 0; j < 4; j++)
                    acc[i][j] = fmaf(avv[i], bvv[j], acc[i][j]);
        }
    }

    if (MODE != 2) {
#pragma unroll
        for (int i = 0; i < 4; i++) {
            int r = row0 + ty * 4 + i;
            if (r < N) {
                size_t idx = (size_t)t * NH + (size_t)r * HDIM + tx * 4;
                uint2 pk;
                pk.x = pack2h(acc[i][0], acc[i][1]);
                pk.y = pack2h(acc[i][2], acc[i][3]);
                *(uint2*)(o16 + idx) = pk;
                if (MODE == 1) {
                    float4 o = make_float4(acc[i][0], acc[i][1], acc[i][2], acc[i][3]);
                    *(float4*)(o32 + idx) = o;
                }
            }
        }
    } else {
        const float a0 = att[0], a1 = att[1], a2 = att[2];
#pragma unroll
        for (int i = 0; i < 4; i++) {
            int r = row0 + ty * 4 + i;
            if (r < N) {
                size_t idx = (size_t)t * NH + (size_t)r * HDIM + tx * 4;
                float4 h4 = *(const float4*)(h1 + idx);
                float4 e4 = *(const float4*)(e1 + idx);
                float hh[4] = {fmaxf(h4.x, 0.f), fmaxf(h4.y, 0.f),
                               fmaxf(h4.z, 0.f), fmaxf(h4.w, 0.f)};
                float ee[4] = {fmaxf(e4.x, 0.f), fmaxf(e4.y, 0.f),
                               fmaxf(e4.z, 0.f), fmaxf(e4.w, 0.f)};
                size_t base = (size_t)t * (size_t)N * 192 + (size_t)r * 192 + tx * 4;
                *(float4*)(outF + base) =
                    make_float4(hh[0] * a0, hh[1] * a0, hh[2] * a0, hh[3] * a0);
                *(float4*)(outF + base + 64) =
                    make_float4(ee[0] * a1, ee[1] * a1, ee[2] * a1, ee[3] * a1);
                *(float4*)(outF + base + 128) =
                    make_float4((acc[i][0] + hh[0]) * a2, (acc[i][1] + hh[1]) * a2,
                                (acc[i][2] + hh[2]) * a2, (acc[i][3] + hh[3]) * a2);
            }
        }
    }
}

// --- CSR build (padded-to-8 segments, interleaved (col,val) pairs) ---------

__global__ __launch_bounds__(256) void hist4(const int* __restrict__ rows,
                                             int* __restrict__ cnt, int E, int N) {
    int e = blockIdx.x * 256 + threadIdx.x;
    int t = blockIdx.y;
    if (e < E) atomicAdd(&cnt[t * N + rows[(size_t)t * E + e]], 1);
}

__global__ __launch_bounds__(256) void scan_sums(const int* __restrict__ cnt,
                                                 int* __restrict__ partials, int M) {
    __shared__ int red[256];
    int base = blockIdx.x * 1024 + threadIdx.x * 4;
    int s = 0;
#pragma unroll
    for (int j = 0; j < 4; j++) {
        int i = base + j;
        if (i < M) s += (cnt[i] + 7) & ~7;
    }
    red[threadIdx.x] = s;
    __syncthreads();
    for (int off = 128; off > 0; off >>= 1) {
        if (threadIdx.x < off) red[threadIdx.x] += red[threadIdx.x + off];
        __syncthreads();
    }
    if (threadIdx.x == 0) partials[blockIdx.x] = red[0];
}

__global__ __launch_bounds__(1024) void scan_partials(int* __restrict__ partials, int B) {
    __shared__ int buf[1024];
    int t = threadIdx.x;
    int v = (t < B) ? partials[t] : 0;
    buf[t] = v;
    __syncthreads();
    for (int off = 1; off < 1024; off <<= 1) {
        int add = (t >= off) ? buf[t - off] : 0;
        __syncthreads();
        buf[t] += add;
        __syncthreads();
    }
    if (t < B) partials[t] = buf[t] - v;  // exclusive
}

__global__ __launch_bounds__(256) void scan_final(int* __restrict__ cnt,
                                                  const int* __restrict__ partials,
                                                  int* __restrict__ start, int M) {
    __shared__ int red[256];
    int tid = threadIdx.x;
    int base = blockIdx.x * 1024 + tid * 4;
    int v[4];
    int s = 0;
#pragma unroll
    for (int j = 0; j < 4; j++) {
        int i = base + j;
        v[j] = (i < M) ? ((cnt[i] + 7) & ~7) : 0;
        s += v[j];
    }
    red[tid] = s;
    __syncthreads();
    int mine = s;
    for (int off = 1; off < 256; off <<= 1) {
        int add = (tid >= off) ? red[tid - off] : 0;
        __syncthreads();
        red[tid] += add;
        __syncthreads();
    }
    int excl = red[tid] - mine + partials[blockIdx.x];
#pragma unroll
    for (int j = 0; j < 4; j++) {
        int i = base + j;
        if (i < M) {
            start[i] = excl;
            cnt[i]   = excl;          // reorder cursor starts at segment base
            excl += v[j];
            if (i == M - 1) start[M] = excl;
        }
    }
}

__global__ __launch_bounds__(256) void reorder4(const int* __restrict__ rows,
                                                const int* __restrict__ cols,
                                                const float* __restrict__ vals,
                                                int* __restrict__ cursor,
                                                int2* __restrict__ spair,
                                                int E, int N) {
    int e = blockIdx.x * 256 + threadIdx.x;
    int t = blockIdx.y;
    if (e >= E) return;
    size_t o = (size_t)t * E + e;
    int pos = atomicAdd(&cursor[t * N + rows[o]], 1);
    spair[pos] = make_int2(cols[o], __float_as_int(vals[o]));   // one 8B store
}

// --- gathers (fp16 tables) -------------------------------------------------
// Pairs: segments padded to %8 with (col=0,val=0). Per 8 edges: 4 uniform
// int4 loads (s_load_dwordx16) + 8 per-lane 2B row loads + 8 fma.

// layer 1 (gather-after): h1_h[row] = sum_{t=2h,2h+1} adj_t-row . hw16_t
// Dual store: fp32 (epilogue residual) + fp16 (layer-2 gather input).
__global__ __launch_bounds__(256) void gatherA(const __half* __restrict__ hw16,
                                               const int* __restrict__ start,
                                               const int4* __restrict__ sp4,
                                               float* __restrict__ h32,
                                               __half* __restrict__ h16, int N) {
    const int half = blockIdx.y;
    const int row  = blockIdx.x * 4 + (threadIdx.x >> 6);
    const int lane = threadIdx.x & 63;
    if (row >= N) return;
    const size_t NH = (size_t)N * HDIM;
    float accA = 0.f, accB = 0.f;

#pragma unroll
    for (int p = 0; p < 2; p++) {
        const int tt = half * 2 + p;
        const __half* __restrict__ h = hw16 + (size_t)tt * NH;
        int beg = __builtin_amdgcn_readfirstlane(start[tt * N + row]);
        int end = __builtin_amdgcn_readfirstlane(start[tt * N + row + 1]);
        for (int e = beg; e < end; e += 8) {
            int c[8]; float v[8];
#pragma unroll
            for (int u = 0; u < 4; u++) {
                int4 q = sp4[(e >> 1) + u];
                c[2 * u]     = q.x; v[2 * u]     = __int_as_float(q.y);
                c[2 * u + 1] = q.z; v[2 * u + 1] = __int_as_float(q.w);
            }
            float hv[8];
#pragma unroll
            for (int u = 0; u < 8; u++)
                hv[u] = __half2float(h[(size_t)c[u] * HDIM + lane]);
#pragma unroll
            for (int u = 0; u < 8; u += 2) {
                accA = fmaf(v[u],     hv[u],     accA);
                accB = fmaf(v[u + 1], hv[u + 1], accB);
            }
        }
    }
    float r = accA + accB;
    size_t idx = (size_t)half * NH + (size_t)row * HDIM + lane;
    h32[idx] = r;
    h16[idx] = __float2half_rn(r);
}

// layers 2-5 (gather-first): g_h[row][p*64+lane] = adj_{2h+p}-row . relu(in16_{p})
__global__ __launch_bounds__(256) void gatherF(const __half* __restrict__ in16,
                                               const int* __restrict__ start,
                                               const int4* __restrict__ sp4,
                                               float* __restrict__ g, int N) {
    const int half = blockIdx.y;
    const int row  = blockIdx.x * 4 + (threadIdx.x >> 6);
    const int lane = threadIdx.x & 63;
    if (row >= N) return;
    const size_t NH = (size_t)N * HDIM;
    float* gout = g + ((size_t)half * N + row) * 128 + lane;

#pragma unroll
    for (int p = 0; p < 2; p++) {
        const int tt = half * 2 + p;
        const __half* __restrict__ h = in16 + (size_t)(tt & 1) * NH;
        int beg = __builtin_amdgcn_readfirstlane(start[tt * N + row]);
        int end = __builtin_amdgcn_readfirstlane(start[tt * N + row + 1]);
        float accA = 0.f, accB = 0.f;
        for (int e = beg; e < end; e += 8) {
            int c[8]; float v[8];
#pragma unroll
            for (int u = 0; u < 4; u++) {
                int4 q = sp4[(e >> 1) + u];
                c[2 * u]     = q.x; v[2 * u]     = __int_as_float(q.y);
                c[2 * u + 1] = q.z; v[2 * u + 1] = __int_as_float(q.w);
            }
            float hv[8];
#pragma unroll
            for (int u = 0; u < 8; u++)
                hv[u] = fmaxf(__half2float(h[(size_t)c[u] * HDIM + lane]), 0.f);
#pragma unroll
            for (int u = 0; u < 8; u += 2) {
                accA = fmaf(v[u],     hv[u],     accA);
                accB = fmaf(v[u + 1], hv[u + 1], accB);
            }
        }
        gout[p * 64] = accA + accB;
    }
}

extern "C" void kernel_launch(void* const* d_in, const int* in_sizes, int n_in,
                              void* d_out, int out_size, void* d_ws, size_t ws_size,
                              hipStream_t stream) {
    const float* feat0 = (const float*)d_in[0];
    const float* feat1 = (const float*)d_in[1];
    const int*   rows  = (const int*)d_in[2];
    const int*   cols  = (const int*)d_in[3];
    const float* vals  = (const float*)d_in[4];
    const float* W1    = (const float*)d_in[5];
    const float* W2    = (const float*)d_in[6];
    const float* W3    = (const float*)d_in[7];
    const float* W4    = (const float*)d_in[8];
    const float* W5    = (const float*)d_in[9];
    const float* att   = (const float*)d_in[10];

    const int N = in_sizes[0] / 128;   // 100000
    const int E = in_sizes[2] / 4;     // 1000000
    const size_t NH = (size_t)N * HDIM;
    const int M = 4 * N;
    const int PadCap = 4 * E + 7 * M;  // max padded CSR entries

    float* ws  = (float*)d_ws;
    float* h10 = ws + 0 * NH;            // h1 fp32 [2NH] (epilogue residual)
    float* e10 = ws + 2 * NH;            // e1 fp32 [2NH] (epilogue)
    float* g   = ws + 4 * NH;            // [2][N][128] fp32; aliases hw16 in L1
    __half* hw16 = (__half*)g;           // [4][N][64] fp16 (layer-1 only)
    __half* f16  = (__half*)(ws + 8 * NH);
    __half* h16  = f16 + 0 * 2 * NH;     // [2][N][64] fp16 each
    __half* e16  = f16 + 1 * 2 * NH;
    __half* a16  = f16 + 2 * 2 * NH;
    __half* b16  = f16 + 3 * 2 * NH;     // f16 region = 8NH halves = 4NH floats

    int2*  spair    = (int2*)(ws + 12 * NH);       // PadCap pairs (16B-aligned)
    int*   start    = (int*)(spair + PadCap);      // M+1
    int*   cursor   = start + (M + 1);             // M
    int*   partials = cursor + M;                  // <=1024

    const int gblk = (N + 63) / 64;
    const int eblk = (E + 255) / 256;
    const int B    = (M + 1023) / 1024;
    const int gr2  = (N + 3) / 4;

    // ---- CSR build (once; graph reused by all 5 layers) ----
    hipMemsetAsync(cursor, 0, (size_t)M * sizeof(int), stream);
    hipMemsetAsync(spair, 0, (size_t)PadCap * sizeof(int2), stream);  // pads -> (0,0)
    hist4<<<dim3(eblk, 4), 256, 0, stream>>>(rows, cursor, E, N);
    scan_sums<<<B, 256, 0, stream>>>(cursor, partials, M);
    scan_partials<<<1, 1024, 0, stream>>>(partials, B);
    scan_final<<<B, 256, 0, stream>>>(cursor, partials, start, M);
    reorder4<<<dim3(eblk, 4), 256, 0, stream>>>(rows, cols, vals, cursor, spair, E, N);

    const int4* sp4 = (const int4*)spair;

    // ---- layer 1: GEMM-first (feat is 128-wide), gather-after ----
    gemm_l1<<<dim3(gblk, 4), 256, 0, stream>>>(feat0, feat1, W1, hw16, N);
    gatherA<<<dim3(gr2, 2), 256, 0, stream>>>(hw16, start, sp4, h10, h16, N);

    // ---- layer 2: gather-first, GEMM stores fp32+fp16 (e1 feeds epilogue) ----
    gatherF<<<dim3(gr2, 2), 256, 0, stream>>>(h16, start, sp4, g, N);
    gemm_h2<1><<<dim3(gblk, 2), 256, 0, stream>>>(g, W2, e16, e10,
                                                  nullptr, nullptr, nullptr, nullptr, N);

    // ---- layers 3-4: gather-first, fp16-only pre-act ----
    gatherF<<<dim3(gr2, 2), 256, 0, stream>>>(e16, start, sp4, g, N);
    gemm_h2<0><<<dim3(gblk, 2), 256, 0, stream>>>(g, W3, a16, nullptr,
                                                  nullptr, nullptr, nullptr, nullptr, N);
    gatherF<<<dim3(gr2, 2), 256, 0, stream>>>(a16, start, sp4, g, N);
    gemm_h2<0><<<dim3(gblk, 2), 256, 0, stream>>>(g, W4, b16, nullptr,
                                                  nullptr, nullptr, nullptr, nullptr, N);

    // ---- layer 5: gather-first + GEMM with fused attention/concat epilogue ----
    gatherF<<<dim3(gr2, 2), 256, 0, stream>>>(b16, start, sp4, g, N);
    gemm_h2<2><<<dim3(gblk, 2), 256, 0, stream>>>(g, W5, nullptr, nullptr,
                                                  h10, e10, att, (float*)d_out, N);
}